// Round 13
// baseline (330.742 us; speedup 1.0000x reference)
//
#include <hip/hip_runtime.h>
#include <hip/hip_bf16.h>
#include <stdint.h>
#include <stddef.h>

#define N_PTS 100000
#define KOFF 27

typedef __attribute__((ext_vector_type(8))) __bf16 bf16x8;
typedef __attribute__((ext_vector_type(4))) float f32x4;
typedef __attribute__((ext_vector_type(8))) unsigned short ushort8;

__device__ inline unsigned short f2bf(float f) {
  union { float f; unsigned u; } x; x.f = f;
  unsigned r = x.u + 0x7fffu + ((x.u >> 16) & 1u);
  return (unsigned short)(r >> 16);
}
__device__ inline float bf2f(unsigned short b) {
  union { unsigned u; float f; } x; x.u = ((unsigned)b) << 16;
  return x.f;
}

// ---------------- prep: W-reorder (phase-major) + feats->split bf16 + zero rows/stats ----
// Wf[kk][k][nt][lane][j] = W[k][c = kk*32 + (lane>>4)*8 + j][d = nt*16 + (lane&15)]
__global__ __launch_bounds__(256) void prep_kernel(const float* __restrict__ feats,
                                                   const float* __restrict__ W1,
                                                   const float* __restrict__ W2,
                                                   unsigned short* __restrict__ flo,
                                                   unsigned short* __restrict__ fhi,
                                                   unsigned short* __restrict__ ylo,
                                                   unsigned short* __restrict__ yhi,
                                                   unsigned short* __restrict__ wf1,
                                                   unsigned short* __restrict__ wf2,
                                                   float* __restrict__ stats) {
  __shared__ float sW[4096];
  int t = threadIdx.x;
  if (blockIdx.x < 54) {
    int which = blockIdx.x & 1;
    int k = blockIdx.x >> 1;
    const float* W = (which ? W2 : W1) + (size_t)k * 4096;
    unsigned short* wf = (which ? wf2 : wf1);
#pragma unroll
    for (int i = 0; i < 4; ++i)
      ((float4*)sW)[t + 256 * i] = ((const float4*)W)[t + 256 * i];
    __syncthreads();
#pragma unroll
    for (int i = 0; i < 16; ++i) {
      int o = i * 256 + t;
      int j = o & 7, l = (o >> 3) & 63, nt = (o >> 9) & 3, kk = (o >> 11) & 1;
      int c = kk * 32 + ((l >> 4) << 3) + j;
      int d = nt * 16 + (l & 15);
      wf[kk * 55296 + k * 2048 + nt * 512 + l * 8 + j] = f2bf(sW[c * 64 + d]);
    }
    return;
  }
  int fb = blockIdx.x - 54;
  int NB = gridDim.x - 54;
  const int NF4 = N_PTS * 16;
  for (int i = fb * 256 + t; i < NF4; i += NB * 256) {
    float4 v = ((const float4*)feats)[i];
    int n = i >> 4, q = i & 15;
    ushort4 o4;
    o4.x = f2bf(v.x); o4.y = f2bf(v.y); o4.z = f2bf(v.z); o4.w = f2bf(v.w);
    if (q < 8) ((ushort4*)(flo + (size_t)n * 32))[q]     = o4;
    else       ((ushort4*)(fhi + (size_t)n * 32))[q - 8] = o4;
  }
  if (fb == 0) {
    if (t < 256) stats[t] = 0.f;
    uint4 z = make_uint4(0u, 0u, 0u, 0u);
    if (t < 4)                ((uint4*)(flo + (size_t)N_PTS * 32))[t]      = z;
    else if (t < 8)           ((uint4*)(fhi + (size_t)N_PTS * 32))[t - 4]  = z;
    else if (t < 12)          ((uint4*)(ylo + (size_t)N_PTS * 32))[t - 8]  = z;
    else if (t < 16)          ((uint4*)(yhi + (size_t)N_PTS * 32))[t - 12] = z;
  }
}

// ---------------- conv: channel-split two-phase gathered GEMM, optional fused BN-in ----
#define MFMA16(a, b, c) __builtin_amdgcn_mfma_f32_16x16x32_bf16(__builtin_bit_cast(bf16x8, a), __builtin_bit_cast(bf16x8, b), c, 0, 0, 0)

// BN transform + mask on a gathered fragment (8 bf16), using phase-local sc8/sh8 regs.
#define XFORM(dst, Asrc, mC)                                                    \
  {                                                                             \
    ushort8 v_ = __builtin_bit_cast(ushort8, Asrc);                             \
    ushort8 o_;                                                                 \
    _Pragma("unroll")                                                           \
    for (int e_ = 0; e_ < 8; ++e_) {                                            \
      float f_ = bf2f(v_[e_]);                                                  \
      o_[e_] = f2bf(fmaxf(f_ * sc8[e_] + sh8[e_], 0.f) * (mC));                 \
    }                                                                           \
    dst = __builtin_bit_cast(uint4, o_);                                        \
  }

// STEP k: capture consumed-tile mask, stage B(k+1), gather A(k+1), prefetch idx/mask(k+2),
// ds_read B(k) + 4 MFMAs (with optional BN transform), ds_write, barrier, flip.
#define STEP(kcur, Ac, An, iN, mN, iF, mF)                                      \
  {                                                                             \
    float mC = mF;                                                              \
    S0 = *(const uint4*)(wfP + (size_t)((kcur) + 1) * 2048 + t8);               \
    {                                                                           \
      int gie = (mN != 0.f) ? iN : N_PTS;                                       \
      An = *(const uint4*)((const char*)finP + (size_t)gie * 64 + g16);         \
    }                                                                           \
    {                                                                           \
      int kf = ((kcur) + 2 <= 26) ? (kcur) + 2 : 26;                            \
      iF = idxp[(size_t)kf * N_PTS];                                            \
      float mt = mp[(size_t)kf * N_PTS]; mF = valid ? mt : 0.f;                 \
    }                                                                           \
    {                                                                           \
      const uint4* bL = (const uint4*)sB[cur];                                  \
      uint4 b0 = bL[lane],       b1 = bL[64 + lane];                            \
      uint4 b2 = bL[128 + lane], b3 = bL[192 + lane];                           \
      uint4 Ax;                                                                 \
      if (dobn) { XFORM(Ax, Ac, mC); } else { Ax = Ac; }                        \
      a0 = MFMA16(Ax, b0, a0); a1 = MFMA16(Ax, b1, a1);                         \
      a2 = MFMA16(Ax, b2, a2); a3 = MFMA16(Ax, b3, a3);                         \
    }                                                                           \
    ((uint4*)sB[cur ^ 1])[t] = S0;                                              \
    __syncthreads();                                                            \
    cur ^= 1;                                                                   \
  }

__global__ __launch_bounds__(256, 4) void conv_kernel(
    const unsigned short* __restrict__ flo,   // [N+1,32] bf16; row N = zeros
    const unsigned short* __restrict__ fhi,   // [N+1,32] bf16; row N = zeros
    const unsigned short* __restrict__ wf,    // [2][27][2048] bf16 phase-major fragments
    const int* __restrict__ idx,              // [K,N]
    const float* __restrict__ mask,           // [K,N] in {0,1}
    const float* __restrict__ bnsum,          // null => no fused BN-in
    const float* __restrict__ bnsq,
    const float* __restrict__ gamma,
    const float* __restrict__ beta,
    unsigned short* __restrict__ ylo,         // [N+1,32] bf16 out (pre-BN)
    unsigned short* __restrict__ yhi,
    float* __restrict__ gsum,                 // [64]
    float* __restrict__ gsq)                  // [64]
{
  __shared__ __align__(16) unsigned char sB[2][4096];
  __shared__ float s_sum[64], s_sq[64];

  int t    = threadIdx.x;
  int lane = t & 63;
  int wid  = t >> 6;
  int m    = lane & 15;
  int g    = lane >> 4;
  int g16  = g * 16;
  size_t t8 = (size_t)t * 8;     // shorts
  int nw   = blockIdx.x * 64 + wid * 16;
  int n    = nw + m;
  bool valid = n < N_PTS;
  int nc   = valid ? n : 0;
  bool dobn = (bnsum != nullptr);

  const int*   idxp = idx + nc;
  const float* mp   = mask + nc;

  if (t < 64) { s_sum[t] = 0.f; s_sq[t] = 0.f; }

  f32x4 a0, a1, a2, a3;
#pragma unroll
  for (int r = 0; r < 4; ++r) { a0[r] = 0.f; a1[r] = 0.f; a2[r] = 0.f; a3[r] = 0.f; }

  for (int p = 0; p < 2; ++p) {
    const unsigned short* finP = p ? fhi : flo;
    const unsigned short* wfP  = wf + (size_t)p * 55296;

    float sc8[8], sh8[8];
    if (dobn) {
#pragma unroll
      for (int e = 0; e < 8; ++e) {
        int c = p * 32 + g * 8 + e;
        float mean = bnsum[c] * (1.f / N_PTS);
        float var  = bnsq[c] * (1.f / N_PTS) - mean * mean;
        float inv  = rsqrtf(var + 1e-5f);
        sc8[e] = gamma[c] * inv;
        sh8[e] = beta[c] - mean * sc8[e];
      }
    } else {
#pragma unroll
      for (int e = 0; e < 8; ++e) { sc8[e] = 1.f; sh8[e] = 0.f; }
    }

    // ---- prologue ----
    uint4 Aa, Ab, S0;
    int iA, iB; float mA, mB;
    int cur = 0;
    iA = idxp[0]; { float mt = mp[0]; mA = valid ? mt : 0.f; }
    S0 = *(const uint4*)(wfP + t8);
    {
      int gie = (mA != 0.f) ? iA : N_PTS;
      Aa = *(const uint4*)((const char*)finP + (size_t)gie * 64 + g16);
    }
    iB = idxp[N_PTS]; { float mt = mp[N_PTS]; mB = valid ? mt : 0.f; }
    ((uint4*)sB[0])[t] = S0;
    __syncthreads();

    // ---- 13 pairs cover k = 0..25 ----
    for (int kk = 0; kk < 13; ++kk) {
      int k = 2 * kk;
      STEP(k,     Aa, Ab, iB, mB, iA, mA);
      STEP(k + 1, Ab, Aa, iA, mA, iB, mB);
    }

    // ---- k = 26, compute only (consumed mask = mA) ----
    {
      const uint4* bL = (const uint4*)sB[cur];
      uint4 b0 = bL[lane],       b1 = bL[64 + lane];
      uint4 b2 = bL[128 + lane], b3 = bL[192 + lane];
      uint4 Ax;
      float mC = mA;
      if (dobn) { XFORM(Ax, Aa, mC); } else { Ax = Aa; }
      a0 = MFMA16(Ax, b0, a0); a1 = MFMA16(Ax, b1, a1);
      a2 = MFMA16(Ax, b2, a2); a3 = MFMA16(Ax, b3, a3);
    }
    __syncthreads();   // sB reuse across phases
  }

  // ---- write y (split bf16) + fused BN stats; C/D: col=lane&15, row=(lane>>4)*4+r ----
  float s0 = 0.f, q0 = 0.f, s1 = 0.f, q1 = 0.f;
  float s2 = 0.f, q2 = 0.f, s3 = 0.f, q3 = 0.f;
#pragma unroll
  for (int r = 0; r < 4; ++r) {
    int row = nw + g * 4 + r;
    float v0 = a0[r]; s0 += v0; q0 += v0 * v0;
    float v1 = a1[r]; s1 += v1; q1 += v1 * v1;
    float v2 = a2[r]; s2 += v2; q2 += v2 * v2;
    float v3 = a3[r]; s3 += v3; q3 += v3 * v3;
    if (row < N_PTS) {
      unsigned short* yl = ylo + (size_t)row * 32;
      unsigned short* yh = yhi + (size_t)row * 32;
      yl[m]      = f2bf(v0);
      yl[16 + m] = f2bf(v1);
      yh[m]      = f2bf(v2);
      yh[16 + m] = f2bf(v3);
    }
  }
  atomicAdd(&s_sum[m],      s0); atomicAdd(&s_sq[m],      q0);
  atomicAdd(&s_sum[16 + m], s1); atomicAdd(&s_sq[16 + m], q1);
  atomicAdd(&s_sum[32 + m], s2); atomicAdd(&s_sq[32 + m], q2);
  atomicAdd(&s_sum[48 + m], s3); atomicAdd(&s_sq[48 + m], q3);
  __syncthreads();
  if (t < 64) {
    atomicAdd(&gsum[t], s_sum[t]);
    atomicAdd(&gsq[t],  s_sq[t]);
  }
}

// ---------------- BN2 + residual + ReLU: split bf16 y2 + f32 feats -> f32 out ----------
__global__ void bn2_kernel(const unsigned short* __restrict__ y2lo,
                           const unsigned short* __restrict__ y2hi,
                           const float* __restrict__ sum,
                           const float* __restrict__ sq,
                           const float* __restrict__ gamma,
                           const float* __restrict__ beta,
                           const float* __restrict__ feats,
                           float* __restrict__ out) {
  __shared__ float s_scale[64], s_shift[64];
  if (threadIdx.x < 64) {
    int c = threadIdx.x;
    float mean = sum[c] * (1.f / N_PTS);
    float var  = sq[c] * (1.f / N_PTS) - mean * mean;
    float inv  = rsqrtf(var + 1e-5f);
    float sc   = gamma[c] * inv;
    s_scale[c] = sc;
    s_shift[c] = beta[c] - mean * sc;
  }
  __syncthreads();
  int tid = blockIdx.x * blockDim.x + threadIdx.x;
  int stride = gridDim.x * blockDim.x;
  const int NT = N_PTS * 4;   // each i: 8 lo-channels + 8 hi-channels of one point
  for (int i = tid; i < NT; i += stride) {
    int n = i >> 2, q = i & 3, c0 = q * 8;
    ushort8 lo = ((const ushort8*)y2lo)[(size_t)n * 4 + q];
    ushort8 hi = ((const ushort8*)y2hi)[(size_t)n * 4 + q];
    const float* fp = feats + (size_t)n * 64 + c0;
    float* op = out + (size_t)n * 64 + c0;
    float4 f0 = ((const float4*)fp)[0];
    float4 f1 = ((const float4*)fp)[1];
    float4 f2 = ((const float4*)(fp + 32))[0];
    float4 f3 = ((const float4*)(fp + 32))[1];
    float4 o0, o1, o2, o3;
    o0.x = fmaxf(bf2f(lo[0]) * s_scale[c0]     + s_shift[c0]     + f0.x, 0.f);
    o0.y = fmaxf(bf2f(lo[1]) * s_scale[c0 + 1] + s_shift[c0 + 1] + f0.y, 0.f);
    o0.z = fmaxf(bf2f(lo[2]) * s_scale[c0 + 2] + s_shift[c0 + 2] + f0.z, 0.f);
    o0.w = fmaxf(bf2f(lo[3]) * s_scale[c0 + 3] + s_shift[c0 + 3] + f0.w, 0.f);
    o1.x = fmaxf(bf2f(lo[4]) * s_scale[c0 + 4] + s_shift[c0 + 4] + f1.x, 0.f);
    o1.y = fmaxf(bf2f(lo[5]) * s_scale[c0 + 5] + s_shift[c0 + 5] + f1.y, 0.f);
    o1.z = fmaxf(bf2f(lo[6]) * s_scale[c0 + 6] + s_shift[c0 + 6] + f1.z, 0.f);
    o1.w = fmaxf(bf2f(lo[7]) * s_scale[c0 + 7] + s_shift[c0 + 7] + f1.w, 0.f);
    int ch = 32 + c0;
    o2.x = fmaxf(bf2f(hi[0]) * s_scale[ch]     + s_shift[ch]     + f2.x, 0.f);
    o2.y = fmaxf(bf2f(hi[1]) * s_scale[ch + 1] + s_shift[ch + 1] + f2.y, 0.f);
    o2.z = fmaxf(bf2f(hi[2]) * s_scale[ch + 2] + s_shift[ch + 2] + f2.z, 0.f);
    o2.w = fmaxf(bf2f(hi[3]) * s_scale[ch + 3] + s_shift[ch + 3] + f2.w, 0.f);
    o3.x = fmaxf(bf2f(hi[4]) * s_scale[ch + 4] + s_shift[ch + 4] + f3.x, 0.f);
    o3.y = fmaxf(bf2f(hi[5]) * s_scale[ch + 5] + s_shift[ch + 5] + f3.y, 0.f);
    o3.z = fmaxf(bf2f(hi[6]) * s_scale[ch + 6] + s_shift[ch + 6] + f3.z, 0.f);
    o3.w = fmaxf(bf2f(hi[7]) * s_scale[ch + 7] + s_shift[ch + 7] + f3.w, 0.f);
    ((float4*)op)[0] = o0;
    ((float4*)op)[1] = o1;
    ((float4*)(op + 32))[0] = o2;
    ((float4*)(op + 32))[1] = o3;
  }
}

// ---------------- launch ----------------
extern "C" void kernel_launch(void* const* d_in, const int* in_sizes, int n_in,
                              void* d_out, int out_size, void* d_ws, size_t ws_size,
                              hipStream_t stream) {
  const float* feats  = (const float*)d_in[0];
  const float* W1     = (const float*)d_in[1];
  const float* gamma1 = (const float*)d_in[2];
  const float* beta1  = (const float*)d_in[3];
  const float* W2     = (const float*)d_in[4];
  const float* gamma2 = (const float*)d_in[5];
  const float* beta2  = (const float*)d_in[6];
  const int*   idx1   = (const int*)d_in[7];
  const float* mask1  = (const float*)d_in[8];
  const int*   idx2   = (const int*)d_in[9];
  const float* mask2  = (const float*)d_in[10];
  float* out = (float*)d_out;

  char* ws = (char*)d_ws;
  unsigned short* flo   = (unsigned short*)(ws + 0);          // (N+1)*64 B = 6,400,128
  unsigned short* fhi   = (unsigned short*)(ws + 6400128);
  unsigned short* ylo   = (unsigned short*)(ws + 12800256);
  unsigned short* yhi   = (unsigned short*)(ws + 19200384);
  unsigned short* wf1   = (unsigned short*)(ws + 25600512);   // 221,184 B
  unsigned short* wf2   = (unsigned short*)(ws + 25821696);   // 221,184 B
  float*          stats = (float*)(ws + 26042880);            // 1,024 B

  float* sum1 = stats;       float* sq1 = stats + 64;
  float* sum2 = stats + 128; float* sq2 = stats + 192;

  prep_kernel<<<54 + 640, 256, 0, stream>>>(feats, W1, W2, flo, fhi, ylo, yhi, wf1, wf2, stats);

  const int CONV_GRID = (N_PTS + 63) / 64;  // 1563
  // conv1: no fused BN-in; writes ylo/yhi + stats1
  conv_kernel<<<CONV_GRID, 256, 0, stream>>>(flo, fhi, wf1, idx1, mask1,
                                             nullptr, nullptr, nullptr, nullptr,
                                             ylo, yhi, sum1, sq1);
  // conv2: fused BN1+ReLU on gathered input; writes y2 into flo/fhi (dead) + stats2
  conv_kernel<<<CONV_GRID, 256, 0, stream>>>(ylo, yhi, wf2, idx2, mask2,
                                             sum1, sq1, gamma1, beta1,
                                             flo, fhi, sum2, sq2);
  bn2_kernel<<<1024, 256, 0, stream>>>(flo, fhi, sum2, sq2, gamma2, beta2, feats, out);
}